// Round 1
// 397.789 us; speedup vs baseline: 1.0638x; 1.0638x over previous
//
#include <hip/hip_runtime.h>
#include <hip/hip_bf16.h>
#include <cstdint>
#include <cstddef>

// B=4, NQ=NK=2048, E=1024, H=16, HD=64, INT=1024.
// Interface (verified r4/r5): inputs f32, output f32, bf16 internals (thr 2%).
typedef __bf16 bf16_t;
typedef __bf16 bf16x8 __attribute__((ext_vector_type(8)));
typedef float f32x4 __attribute__((ext_vector_type(4)));
typedef float f32x16 __attribute__((ext_vector_type(16)));
typedef uint32_t u32;

#define EDIM 1024
#define HH 16
#define HD 64
#define NSEQ 2048
// fold 1/sqrt(64) * log2(e) into Q so softmax uses native exp2
#define QSCALE 0.18033688011f

__device__ __forceinline__ void async_copy16(const bf16_t* gsrc, bf16_t* lds_dst) {
    __builtin_amdgcn_global_load_lds(
        (const __attribute__((address_space(1))) uint32_t*)gsrc,
        (__attribute__((address_space(3))) uint32_t*)lds_dst,
        16, 0, 0);
}

// ---------------------------------------------------------------------------
// f32 -> bf16 bulk convert (8 elems/thread, exact cover for 8M elems).
// ---------------------------------------------------------------------------
__global__ void cvt_f32_bf16(const float* __restrict__ in, bf16_t* __restrict__ out) {
    size_t i = ((size_t)blockIdx.x * 256 + threadIdx.x) * 8;
    float4 x = *(const float4*)(in + i);
    float4 y = *(const float4*)(in + i + 4);
    bf16x8 v = {(bf16_t)x.x, (bf16_t)x.y, (bf16_t)x.z, (bf16_t)x.w,
                (bf16_t)y.x, (bf16_t)y.y, (bf16_t)y.z, (bf16_t)y.w};
    *(bf16x8*)(out + i) = v;
}

// ---------------------------------------------------------------------------
// Weight transpose + bf16 convert: W (1024x1024, KxN, f32) -> WT (NxK, bf16).
// ---------------------------------------------------------------------------
__global__ void transpose_all(const float* __restrict__ w0, const float* __restrict__ w1,
                              const float* __restrict__ w2, const float* __restrict__ w3,
                              bf16_t* __restrict__ o0, bf16_t* __restrict__ o1,
                              bf16_t* __restrict__ o2, bf16_t* __restrict__ o3) {
    __shared__ bf16_t t[64][65];
    const float* in;
    bf16_t* out;
    switch (blockIdx.z) {
        case 0: in = w0; out = o0; break;
        case 1: in = w1; out = o1; break;
        case 2: in = w2; out = o2; break;
        default: in = w3; out = o3; break;
    }
    const int tid = threadIdx.x;
    const int kt = blockIdx.x, nt = blockIdx.y;
    #pragma unroll
    for (int i = 0; i < 16; i++) {
        int idx = i * 256 + tid;
        int r = idx >> 6, c = idx & 63;
        t[r][c] = (bf16_t)in[(size_t)(kt * 64 + r) * 1024 + nt * 64 + c];
    }
    __syncthreads();
    #pragma unroll
    for (int i = 0; i < 16; i++) {
        int idx = i * 256 + tid;
        int r = idx >> 6, c = idx & 63;
        out[(size_t)(nt * 64 + r) * 1024 + kt * 64 + c] = t[c][r];
    }
}

// ---------------------------------------------------------------------------
// NT GEMM: C(MxN) = A(MxK) * Bt(NxK)^T + bias. 128x128 tile, BK=32.
// LDS XOR-swizzled (4 chunks/row, key (row>>1)&3): frag reads 2-way (free).
// AB=0: A f32 (inline convert). AB=1: A bf16 (async global_load_lds).
// MODE 0: head-major [b][h][n][d] bf16 * oscale   (Q, K projections)
// MODE 1: transposed [b][h][d][n] bf16            (V projection)
// MODE 2: row-major MxN, OUT dtype                (output projection)
// ---------------------------------------------------------------------------
template <int AB, int MODE, typename OUT>
__global__ __launch_bounds__(256, 2)
void gemm_nt(const void* __restrict__ Araw, const bf16_t* __restrict__ Bt,
             const float* __restrict__ bias, OUT* __restrict__ C,
             int M, int N, int K, float oscale) {
    constexpr int BM = 128, BN = 128, BK = 32;
    __shared__ bf16_t Asm[BM * BK];
    __shared__ bf16_t Bsm[BN * BK];
    const int tid = threadIdx.x;
    const int wave = tid >> 6, lane = tid & 63;
    const int quad = lane >> 4, l15 = lane & 15;
    const int n0 = blockIdx.x * BN;   // x = N-tile: consecutive blocks share A-panel
    const int m0 = blockIdx.y * BM;
    const int wm = (wave & 1) * 64, wn = (wave >> 1) * 64;

    f32x4 acc[4][4] = {};

    for (int k0 = 0; k0 < K; k0 += BK) {
        __syncthreads();
        if (AB) {
            const bf16_t* A = (const bf16_t*)Araw;
            #pragma unroll
            for (int i = 0; i < 2; i++) {
                int s = i * 256 + tid;
                int row = s >> 2, c = s & 3;
                int kc = c ^ ((row >> 1) & 3);
                async_copy16(A + (size_t)(m0 + row) * K + k0 + kc * 8, Asm + s * 8);
            }
        } else {
            const float* A = (const float*)Araw;
            #pragma unroll
            for (int i = 0; i < 2; i++) {
                int s = i * 256 + tid;
                int row = s >> 2, c = s & 3;
                int kc = c ^ ((row >> 1) & 3);
                const float* sp = A + (size_t)(m0 + row) * K + k0 + kc * 8;
                float4 x = *(const float4*)sp;
                float4 y = *(const float4*)(sp + 4);
                bf16x8 vv = {(bf16_t)x.x, (bf16_t)x.y, (bf16_t)x.z, (bf16_t)x.w,
                             (bf16_t)y.x, (bf16_t)y.y, (bf16_t)y.z, (bf16_t)y.w};
                *(bf16x8*)&Asm[s * 8] = vv;
            }
        }
        #pragma unroll
        for (int i = 0; i < 2; i++) {
            int s = i * 256 + tid;
            int row = s >> 2, c = s & 3;
            int kc = c ^ ((row >> 1) & 3);
            async_copy16(Bt + (size_t)(n0 + row) * K + k0 + kc * 8, Bsm + s * 8);
        }
        __syncthreads();

        bf16x8 af[4], bfr[4];
        #pragma unroll
        for (int mi = 0; mi < 4; mi++) {
            int row = wm + mi * 16 + l15;
            af[mi] = *(const bf16x8*)&Asm[row * BK + ((quad ^ ((row >> 1) & 3)) * 8)];
        }
        #pragma unroll
        for (int ni = 0; ni < 4; ni++) {
            int row = wn + ni * 16 + l15;
            bfr[ni] = *(const bf16x8*)&Bsm[row * BK + ((quad ^ ((row >> 1) & 3)) * 8)];
        }
        #pragma unroll
        for (int mi = 0; mi < 4; mi++)
            #pragma unroll
            for (int ni = 0; ni < 4; ni++)
                acc[mi][ni] = __builtin_amdgcn_mfma_f32_16x16x32_bf16(
                    af[mi], bfr[ni], acc[mi][ni], 0, 0, 0);
    }

    // Epilogue. C/D layout: row = quad*4 + r, col = l15 (verified m89/m91).
    #pragma unroll
    for (int mi = 0; mi < 4; mi++) {
        #pragma unroll
        for (int ni = 0; ni < 4; ni++) {
            #pragma unroll
            for (int r = 0; r < 4; r++) {
                int m = m0 + wm + mi * 16 + quad * 4 + r;
                int nch = n0 + wn + ni * 16 + l15;
                float v = (acc[mi][ni][r] + bias[nch]) * oscale;
                if (MODE == 2) {
                    C[(size_t)m * N + nch] = (OUT)v;
                } else {
                    int b = m >> 11, n = m & 2047;
                    int h = nch >> 6, d = nch & 63;
                    if (MODE == 0)
                        C[(((size_t)(b * HH + h)) * NSEQ + n) * HD + d] = (OUT)v;
                    else
                        C[(((size_t)(b * HH + h)) * HD + d) * NSEQ + n] = (OUT)v;
                }
            }
        }
    }
}

// ---------------------------------------------------------------------------
// Flash attention, swapped-QK^T in-register softmax (m214 structure).
// Grid 1024 blocks x 256 thr (4 waves). Wave owns 32 q-rows; kv-tile 64;
// 32 iters. XCD clustering: xcd=B&7, qt=(B>>3)&15, bh=(B>>7)*8+xcd (all 16
// q-blocks of a bh on one XCD -> 512 KB K/V slab L2-resident, 8 bh/XCD).
//
// QK^T computed SWAPPED: S^T = mfma_32x32x16(A=K, B=Q) so each lane holds a
// full P column (q = lane&31) in registers: p[r] = P[q][(r&3)+8*(r>>2)+4*hi].
// Softmax fully in-register (fixed-max: Q pre-scaled, p=exp2(s)); P->bf16
// pack (cvt_pk pairs) + half-swap across the lane-32 halves assembles PV's
// A-fragments directly -- NO P round-trip through LDS.
// K/V double-buffered in LDS, one barrier per iter: issue next tile's
// global_load_lds right after the barrier, compute current, next barrier's
// implicit vmcnt(0) drains under the compute (T3 minimum 2-phase).
// Qh, Kh: [bh][n][d] bf16. Vt: [bh][d][n] bf16. Out ao: [b][n][INT] bf16.
// ---------------------------------------------------------------------------
union PW { u32 w[4]; bf16x8 v; };

__device__ __forceinline__ u32 pack_bf16(float lo, float hi) {
    union { bf16_t h[2]; u32 u; } x;
    x.h[0] = (bf16_t)lo;
    x.h[1] = (bf16_t)hi;
    return x.u;   // compiler emits v_cvt_pk_bf16_f32
}

// Transpose the 2x2 (register x lane-half) arrangement:
// a' = {a.lo_half, b.lo_half}, b' = {a.hi_half, b.hi_half}.
// (Semantics-safe form of v_permlane32_swap via shfl_xor + cndmask.)
__device__ __forceinline__ void half_swap(u32& a, u32& b, int hi) {
    u32 as = (u32)__shfl_xor((int)a, 32, 64);
    u32 bs = (u32)__shfl_xor((int)b, 32, 64);
    a = hi ? bs : a;
    b = hi ? b : as;
}

// p[r] of one 32x32 S^T tile -> exp2 -> two PV A-frags (kv 0..15, 16..31).
__device__ __forceinline__ void softmax_pack(const f32x16 sa, float* lp, int hi,
                                             PW& f0, PW& f1) {
    float p[16];
    #pragma unroll
    for (int r = 0; r < 16; r++) {
        p[r] = exp2f(sa[r]);
        lp[r & 3] += p[r];   // 4 partial chains (breaks serial fadd dep)
    }
    u32 x0 = pack_bf16(p[0],  p[1]),  x1 = pack_bf16(p[2],  p[3]);
    u32 x2 = pack_bf16(p[4],  p[5]),  x3 = pack_bf16(p[6],  p[7]);
    u32 x4 = pack_bf16(p[8],  p[9]),  x5 = pack_bf16(p[10], p[11]);
    u32 x6 = pack_bf16(p[12], p[13]), x7 = pack_bf16(p[14], p[15]);
    half_swap(x0, x2, hi); half_swap(x1, x3, hi);
    half_swap(x4, x6, hi); half_swap(x5, x7, hi);
    f0.w[0] = x0; f0.w[1] = x1; f0.w[2] = x2; f0.w[3] = x3;
    f1.w[0] = x4; f1.w[1] = x5; f1.w[2] = x6; f1.w[3] = x7;
}

__global__ __launch_bounds__(256, 4)
void attn_kernel(const bf16_t* __restrict__ Qh, const bf16_t* __restrict__ Kh,
                 const bf16_t* __restrict__ Vt, bf16_t* __restrict__ out) {
    __shared__ bf16_t Ks[2][64 * 64];   // 16 KB: kv-tile, [kv][d], chunk-swizzled
    __shared__ bf16_t Vs[2][64 * 64];   // 16 KB: kv-tile, [d][kv], chunk-swizzled
    const int tid = threadIdx.x, wave = tid >> 6, lane = tid & 63;
    const int l31 = lane & 31, hi = lane >> 5;
    const int B = blockIdx.x;
    const int qt = (B >> 3) & 15;
    const int bh = (B >> 7) * 8 + (B & 7);
    const int b = bh >> 4, h = bh & 15;

    const bf16_t* kbase = Kh + (size_t)bh * NSEQ * HD;
    const bf16_t* vbase = Vt + (size_t)bh * HD * NSEQ;

    // Hoist Q fragments straight from global (B-operand of swapped QK^T):
    // lane holds Q[q = qt*128 + wave*32 + l31][d = s*16 + hi*8 + j].
    bf16x8 qf[4];
    {
        const bf16_t* qrow =
            Qh + ((size_t)bh * NSEQ + qt * 128 + wave * 32 + l31) * HD + hi * 8;
        #pragma unroll
        for (int s = 0; s < 4; s++) qf[s] = *(const bf16x8*)(qrow + s * 16);
    }

    // Staging source pointers: thread covers chunks tid and tid+256 of the
    // 512-chunk (64 rows x 8) tile. LDS linear, global source pre-swizzled
    // (slot c holds global chunk c^(row&7)).
    const bf16_t *ks0, *ks1, *vs0, *vs1;
    {
        int r0 = tid >> 3, c0 = tid & 7;
        int s1 = tid + 256;
        int r1 = s1 >> 3, c1 = s1 & 7;
        ks0 = kbase + r0 * HD + (c0 ^ (r0 & 7)) * 8;
        ks1 = kbase + r1 * HD + (c1 ^ (r1 & 7)) * 8;
        vs0 = vbase + (size_t)r0 * NSEQ + (c0 ^ (r0 & 7)) * 8;
        vs1 = vbase + (size_t)r1 * NSEQ + (c1 ^ (r1 & 7)) * 8;
    }

    // Prologue: stage tile 0 into buffer 0.
    async_copy16(ks0, &Ks[0][tid * 8]);
    async_copy16(ks1, &Ks[0][(tid + 256) * 8]);
    async_copy16(vs0, &Vs[0][tid * 8]);
    async_copy16(vs1, &Vs[0][(tid + 256) * 8]);

    f32x16 oacc[2] = {};       // [d-tile]: O[q 32][d 32], row=q col=d
    float lp[4] = {};          // softmax denominator partials

    for (int t = 0; t < 32; t++) {
        const int cur = t & 1;
        __syncthreads();   // drains vmcnt -> tile t ready; prev reads of buf cur^1 done

        if (t < 31) {      // issue next tile into the other buffer (in flight across compute)
            ks0 += 64 * HD; ks1 += 64 * HD;
            vs0 += 64;      vs1 += 64;
            async_copy16(ks0, &Ks[cur ^ 1][tid * 8]);
            async_copy16(ks1, &Ks[cur ^ 1][(tid + 256) * 8]);
            async_copy16(vs0, &Vs[cur ^ 1][tid * 8]);
            async_copy16(vs1, &Vs[cur ^ 1][(tid + 256) * 8]);
        }

        // S^T = K Q^T: rows = kv (2 tiles of 32), cols = this wave's 32 q.
        f32x16 sacc0 = {};
        f32x16 sacc1 = {};
        #pragma unroll
        for (int s = 0; s < 4; s++) {
            int g = s * 2 + hi;           // d-chunk index
            int row0 = l31;               // kv 0..31
            int row1 = 32 + l31;          // kv 32..63
            bf16x8 ak0 = *(const bf16x8*)&Ks[cur][row0 * 64 + ((g ^ (row0 & 7)) * 8)];
            bf16x8 ak1 = *(const bf16x8*)&Ks[cur][row1 * 64 + ((g ^ (row1 & 7)) * 8)];
            sacc0 = __builtin_amdgcn_mfma_f32_32x32x16_bf16(ak0, qf[s], sacc0, 0, 0, 0);
            sacc1 = __builtin_amdgcn_mfma_f32_32x32x16_bf16(ak1, qf[s], sacc1, 0, 0, 0);
        }

        // In-register softmax + pack into 4 PV A-frags (kv 0..15,16..31,32..47,48..63)
        PW pa[4];
        softmax_pack(sacc0, lp, hi, pa[0], pa[1]);
        softmax_pack(sacc1, lp, hi, pa[2], pa[3]);

        // O += P V
        #pragma unroll
        for (int dt = 0; dt < 2; dt++) {
            #pragma unroll
            for (int ks = 0; ks < 4; ks++) {
                int row = dt * 32 + l31;          // d row in Vs
                int g = ks * 2 + hi;              // kv-chunk index
                bf16x8 bv = *(const bf16x8*)&Vs[cur][row * 64 + ((g ^ (row & 7)) * 8)];
                oacc[dt] = __builtin_amdgcn_mfma_f32_32x32x16_bf16(
                    pa[ks].v, bv, oacc[dt], 0, 0, 0);
            }
        }
    }

    // l[q] lives at lane q (both halves after xor-32 add); redistribute per reg.
    float lsum = (lp[0] + lp[1]) + (lp[2] + lp[3]);
    lsum += __shfl_xor(lsum, 32, 64);
    float linv = 1.f / lsum;
    float rinv[16];
    #pragma unroll
    for (int r = 0; r < 16; r++) {
        int q = (r & 3) + 8 * (r >> 2) + 4 * hi;
        rinv[r] = __shfl(linv, q, 64);
    }

    const int n0 = qt * 128 + wave * 32;
    #pragma unroll
    for (int dt = 0; dt < 2; dt++) {
        int c = h * 64 + dt * 32 + l31;
        #pragma unroll
        for (int r = 0; r < 16; r++) {
            int q = (r & 3) + 8 * (r >> 2) + 4 * hi;
            out[((size_t)b * NSEQ + n0 + q) * EDIM + c] = (bf16_t)(oacc[dt][r] * rinv[r]);
        }
    }
}

// ---------------------------------------------------------------------------
extern "C" void kernel_launch(void* const* d_in, const int* in_sizes, int n_in,
                              void* d_out, int out_size, void* d_ws, size_t ws_size,
                              hipStream_t stream) {
    const float* q  = (const float*)d_in[0];
    const float* k  = (const float*)d_in[1];
    const float* v  = (const float*)d_in[2];
    const float* wq = (const float*)d_in[3];
    const float* bq = (const float*)d_in[4];
    const float* wk = (const float*)d_in[5];
    const float* bk = (const float*)d_in[6];
    const float* wv = (const float*)d_in[7];
    const float* bv = (const float*)d_in[8];
    const float* wo = (const float*)d_in[9];
    const float* bo = (const float*)d_in[10];
    float* out = (float*)d_out;

    char* ws = (char*)d_ws;
    bf16_t* wqt = (bf16_t*)(ws + ((size_t)0  << 20)); // 2 MB each, bf16 NxK
    bf16_t* wkt = (bf16_t*)(ws + ((size_t)2  << 20));
    bf16_t* wvt = (bf16_t*)(ws + ((size_t)4  << 20));
    bf16_t* wot = (bf16_t*)(ws + ((size_t)6  << 20));

    const bool big = ws_size >= ((size_t)90 << 20);
    size_t off = big ? ((size_t)24 << 20) : ((size_t)8 << 20);
    bf16_t* X   = (bf16_t*)(ws + ((size_t)8 << 20));  // 16 MB bf16 A scratch (big only)
    bf16_t* Qh  = (bf16_t*)(ws + off);                              // 16 MB [b][h][n][d]
    bf16_t* Kh  = (bf16_t*)(ws + off + ((size_t)16 << 20));         // 16 MB [b][h][n][d]
    bf16_t* Vt  = (bf16_t*)(ws + off + ((size_t)32 << 20));         // 16 MB [b][h][d][n]
    bf16_t* ao  = (bf16_t*)(ws + off + ((size_t)48 << 20));         // 16 MB [b][n][INT]

    dim3 tb(256);

    transpose_all<<<dim3(16, 16, 4), tb, 0, stream>>>(wq, wk, wv, wo, wqt, wkt, wvt, wot);

    dim3 gg(8, 64);  // x = N-tiles (8), y = M-tiles (64): A-panel sharing
    if (big) {
        // Pre-convert A once -> pure async staging in the GEMMs (serialized reuse of X).
        cvt_f32_bf16<<<4096, tb, 0, stream>>>(q, X);
        gemm_nt<1, 0, bf16_t><<<gg, tb, 0, stream>>>(X, wqt, bq, Qh, 8192, 1024, 1024, QSCALE);
        cvt_f32_bf16<<<4096, tb, 0, stream>>>(k, X);
        gemm_nt<1, 0, bf16_t><<<gg, tb, 0, stream>>>(X, wkt, bk, Kh, 8192, 1024, 1024, 1.0f);
        cvt_f32_bf16<<<4096, tb, 0, stream>>>(v, X);
        gemm_nt<1, 1, bf16_t><<<gg, tb, 0, stream>>>(X, wvt, bv, Vt, 8192, 1024, 1024, 1.0f);
    } else {
        gemm_nt<0, 0, bf16_t><<<gg, tb, 0, stream>>>(q, wqt, bq, Qh, 8192, 1024, 1024, QSCALE);
        gemm_nt<0, 0, bf16_t><<<gg, tb, 0, stream>>>(k, wkt, bk, Kh, 8192, 1024, 1024, 1.0f);
        gemm_nt<0, 1, bf16_t><<<gg, tb, 0, stream>>>(v, wvt, bv, Vt, 8192, 1024, 1024, 1.0f);
    }

    attn_kernel<<<1024, tb, 0, stream>>>(Qh, Kh, Vt, ao);

    gemm_nt<1, 2, float><<<gg, tb, 0, stream>>>(ao, wot, bo, out, 8192, 1024, 1024, 1.0f);
}

// Round 2
// 371.177 us; speedup vs baseline: 1.1400x; 1.0717x over previous
//
#include <hip/hip_runtime.h>
#include <hip/hip_bf16.h>
#include <cstdint>
#include <cstddef>

// B=4, NQ=NK=2048, E=1024, H=16, HD=64, INT=1024.
// Interface (verified r4/r5): inputs f32, output f32, bf16 internals (thr 2%).
typedef __bf16 bf16_t;
typedef __bf16 bf16x8 __attribute__((ext_vector_type(8)));
typedef float f32x4 __attribute__((ext_vector_type(4)));
typedef float f32x16 __attribute__((ext_vector_type(16)));
typedef uint32_t u32;

#define EDIM 1024
#define HH 16
#define HD 64
#define NSEQ 2048
// fold 1/sqrt(64) * log2(e) into Q so softmax uses native exp2
#define QSCALE 0.18033688011f

__device__ __forceinline__ void async_copy16(const bf16_t* gsrc, bf16_t* lds_dst) {
    __builtin_amdgcn_global_load_lds(
        (const __attribute__((address_space(1))) uint32_t*)gsrc,
        (__attribute__((address_space(3))) uint32_t*)lds_dst,
        16, 0, 0);
}

// ---------------------------------------------------------------------------
// f32 -> bf16 bulk convert (8 elems/thread, exact cover for 8M elems).
// ---------------------------------------------------------------------------
__global__ void cvt_f32_bf16(const float* __restrict__ in, bf16_t* __restrict__ out) {
    size_t i = ((size_t)blockIdx.x * 256 + threadIdx.x) * 8;
    float4 x = *(const float4*)(in + i);
    float4 y = *(const float4*)(in + i + 4);
    bf16x8 v = {(bf16_t)x.x, (bf16_t)x.y, (bf16_t)x.z, (bf16_t)x.w,
                (bf16_t)y.x, (bf16_t)y.y, (bf16_t)y.z, (bf16_t)y.w};
    *(bf16x8*)(out + i) = v;
}

// ---------------------------------------------------------------------------
// Weight transpose + bf16 convert: W (1024x1024, KxN, f32) -> WT (NxK, bf16).
// ---------------------------------------------------------------------------
__global__ void transpose_all(const float* __restrict__ w0, const float* __restrict__ w1,
                              const float* __restrict__ w2, const float* __restrict__ w3,
                              bf16_t* __restrict__ o0, bf16_t* __restrict__ o1,
                              bf16_t* __restrict__ o2, bf16_t* __restrict__ o3) {
    __shared__ bf16_t t[64][65];
    const float* in;
    bf16_t* out;
    switch (blockIdx.z) {
        case 0: in = w0; out = o0; break;
        case 1: in = w1; out = o1; break;
        case 2: in = w2; out = o2; break;
        default: in = w3; out = o3; break;
    }
    const int tid = threadIdx.x;
    const int kt = blockIdx.x, nt = blockIdx.y;
    #pragma unroll
    for (int i = 0; i < 16; i++) {
        int idx = i * 256 + tid;
        int r = idx >> 6, c = idx & 63;
        t[r][c] = (bf16_t)in[(size_t)(kt * 64 + r) * 1024 + nt * 64 + c];
    }
    __syncthreads();
    #pragma unroll
    for (int i = 0; i < 16; i++) {
        int idx = i * 256 + tid;
        int r = idx >> 6, c = idx & 63;
        out[(size_t)(nt * 64 + r) * 1024 + kt * 64 + c] = t[c][r];
    }
}

// ---------------------------------------------------------------------------
// NT GEMM: C(MxN) = A(MxK) * Bt(NxK)^T + bias. 128x128 tile, BK=32.
// LDS XOR-swizzled (4 chunks/row, key (row>>1)&3): frag reads 2-way (free).
// AB=0: A f32 (inline convert). AB=1: A bf16 (async global_load_lds).
// MODE 0: head-major [b][h][n][d] bf16 * oscale   (Q, K projections)
// MODE 1: transposed [b][h][d][n] bf16            (V projection)
// MODE 2: row-major MxN, OUT dtype                (output projection)
// ---------------------------------------------------------------------------
template <int AB, int MODE, typename OUT>
__global__ __launch_bounds__(256, 2)
void gemm_nt(const void* __restrict__ Araw, const bf16_t* __restrict__ Bt,
             const float* __restrict__ bias, OUT* __restrict__ C,
             int M, int N, int K, float oscale) {
    constexpr int BM = 128, BN = 128, BK = 32;
    __shared__ bf16_t Asm[BM * BK];
    __shared__ bf16_t Bsm[BN * BK];
    const int tid = threadIdx.x;
    const int wave = tid >> 6, lane = tid & 63;
    const int quad = lane >> 4, l15 = lane & 15;
    const int n0 = blockIdx.x * BN;   // x = N-tile: consecutive blocks share A-panel
    const int m0 = blockIdx.y * BM;
    const int wm = (wave & 1) * 64, wn = (wave >> 1) * 64;

    f32x4 acc[4][4] = {};

    for (int k0 = 0; k0 < K; k0 += BK) {
        __syncthreads();
        if (AB) {
            const bf16_t* A = (const bf16_t*)Araw;
            #pragma unroll
            for (int i = 0; i < 2; i++) {
                int s = i * 256 + tid;
                int row = s >> 2, c = s & 3;
                int kc = c ^ ((row >> 1) & 3);
                async_copy16(A + (size_t)(m0 + row) * K + k0 + kc * 8, Asm + s * 8);
            }
        } else {
            const float* A = (const float*)Araw;
            #pragma unroll
            for (int i = 0; i < 2; i++) {
                int s = i * 256 + tid;
                int row = s >> 2, c = s & 3;
                int kc = c ^ ((row >> 1) & 3);
                const float* sp = A + (size_t)(m0 + row) * K + k0 + kc * 8;
                float4 x = *(const float4*)sp;
                float4 y = *(const float4*)(sp + 4);
                bf16x8 vv = {(bf16_t)x.x, (bf16_t)x.y, (bf16_t)x.z, (bf16_t)x.w,
                             (bf16_t)y.x, (bf16_t)y.y, (bf16_t)y.z, (bf16_t)y.w};
                *(bf16x8*)&Asm[s * 8] = vv;
            }
        }
        #pragma unroll
        for (int i = 0; i < 2; i++) {
            int s = i * 256 + tid;
            int row = s >> 2, c = s & 3;
            int kc = c ^ ((row >> 1) & 3);
            async_copy16(Bt + (size_t)(n0 + row) * K + k0 + kc * 8, Bsm + s * 8);
        }
        __syncthreads();

        bf16x8 af[4], bfr[4];
        #pragma unroll
        for (int mi = 0; mi < 4; mi++) {
            int row = wm + mi * 16 + l15;
            af[mi] = *(const bf16x8*)&Asm[row * BK + ((quad ^ ((row >> 1) & 3)) * 8)];
        }
        #pragma unroll
        for (int ni = 0; ni < 4; ni++) {
            int row = wn + ni * 16 + l15;
            bfr[ni] = *(const bf16x8*)&Bsm[row * BK + ((quad ^ ((row >> 1) & 3)) * 8)];
        }
        #pragma unroll
        for (int mi = 0; mi < 4; mi++)
            #pragma unroll
            for (int ni = 0; ni < 4; ni++)
                acc[mi][ni] = __builtin_amdgcn_mfma_f32_16x16x32_bf16(
                    af[mi], bfr[ni], acc[mi][ni], 0, 0, 0);
    }

    // Epilogue. C/D layout: row = quad*4 + r, col = l15 (verified m89/m91).
    #pragma unroll
    for (int mi = 0; mi < 4; mi++) {
        #pragma unroll
        for (int ni = 0; ni < 4; ni++) {
            #pragma unroll
            for (int r = 0; r < 4; r++) {
                int m = m0 + wm + mi * 16 + quad * 4 + r;
                int nch = n0 + wn + ni * 16 + l15;
                float v = (acc[mi][ni][r] + bias[nch]) * oscale;
                if (MODE == 2) {
                    C[(size_t)m * N + nch] = (OUT)v;
                } else {
                    int b = m >> 11, n = m & 2047;
                    int h = nch >> 6, d = nch & 63;
                    if (MODE == 0)
                        C[(((size_t)(b * HH + h)) * NSEQ + n) * HD + d] = (OUT)v;
                    else
                        C[(((size_t)(b * HH + h)) * HD + d) * NSEQ + n] = (OUT)v;
                }
            }
        }
    }
}

// ---------------------------------------------------------------------------
// Flash attention, swapped-QK^T in-register softmax (m214 structure).
// Grid 1024 blocks x 256 thr (4 waves). Wave owns 32 q-rows; kv-tile 64;
// 32 iters. XCD clustering: xcd=B&7, qt=(B>>3)&15, bh=(B>>7)*8+xcd (all 16
// q-blocks of a bh on one XCD -> 512 KB K/V slab L2-resident, 8 bh/XCD).
//
// QK^T computed SWAPPED: S^T = mfma_32x32x16(A=K, B=Q) so each lane holds a
// full P column (q = lane&31) in registers: p[r] = P[q][(r&3)+8*(r>>2)+4*hi].
// Softmax fully in-register (fixed-max: Q pre-scaled, p=exp2(s)); P->bf16
// pack (v_cvt_pk) + v_permlane32_swap assembles PV's A-fragments directly --
// NO P round-trip through LDS, no ds_bpermute.
// K/V double-buffered in LDS, one barrier per iter (T3 minimum 2-phase).
// launch_bounds(256,2): 256 unified regs/wave so sacc/oacc/pa all live in
// VGPRs -- no v_accvgpr_read/write traffic in the softmax (the round-1
// 128-reg cap forced a 64V+64A split and VALU-bound accvgpr copies).
// Qh, Kh: [bh][n][d] bf16. Vt: [bh][d][n] bf16. Out ao: [b][n][INT] bf16.
// ---------------------------------------------------------------------------
union PW { u32 w[4]; bf16x8 v; };

__device__ __forceinline__ u32 pack_bf16(float lo, float hi) {
    union { bf16_t h[2]; u32 u; } x;
    x.h[0] = (bf16_t)lo;
    x.h[1] = (bf16_t)hi;
    return x.u;   // compiler emits v_cvt_pk_bf16_f32
}

// v_permlane32_swap_b32: new_a = {a.lanes0-31, b.lanes0-31},
//                        new_b = {a.lanes32-63, b.lanes32-63}.
__device__ __forceinline__ void half_swap(u32& a, u32& b) {
    auto r = __builtin_amdgcn_permlane32_swap(a, b, false, false);
    a = r[0];
    b = r[1];
}

// p[r] of one 32x32 S^T tile -> exp2 -> two PV A-frags (kv 0..15, 16..31).
__device__ __forceinline__ void softmax_pack(const f32x16 sa, float* lp,
                                             PW& f0, PW& f1) {
    float p[16];
    #pragma unroll
    for (int r = 0; r < 16; r++) {
        p[r] = __builtin_amdgcn_exp2f(sa[r]);   // single v_exp_f32
        lp[r & 3] += p[r];   // 4 partial chains (breaks serial fadd dep)
    }
    u32 x0 = pack_bf16(p[0],  p[1]),  x1 = pack_bf16(p[2],  p[3]);
    u32 x2 = pack_bf16(p[4],  p[5]),  x3 = pack_bf16(p[6],  p[7]);
    u32 x4 = pack_bf16(p[8],  p[9]),  x5 = pack_bf16(p[10], p[11]);
    u32 x6 = pack_bf16(p[12], p[13]), x7 = pack_bf16(p[14], p[15]);
    half_swap(x0, x2); half_swap(x1, x3);
    half_swap(x4, x6); half_swap(x5, x7);
    f0.w[0] = x0; f0.w[1] = x1; f0.w[2] = x2; f0.w[3] = x3;
    f1.w[0] = x4; f1.w[1] = x5; f1.w[2] = x6; f1.w[3] = x7;
}

__global__ __launch_bounds__(256, 2)
void attn_kernel(const bf16_t* __restrict__ Qh, const bf16_t* __restrict__ Kh,
                 const bf16_t* __restrict__ Vt, bf16_t* __restrict__ out) {
    __shared__ bf16_t Ks[2][64 * 64];   // 16 KB: kv-tile, [kv][d], chunk-swizzled
    __shared__ bf16_t Vs[2][64 * 64];   // 16 KB: kv-tile, [d][kv], chunk-swizzled
    const int tid = threadIdx.x, wave = tid >> 6, lane = tid & 63;
    const int l31 = lane & 31, hi = lane >> 5;
    const int B = blockIdx.x;
    const int qt = (B >> 3) & 15;
    const int bh = (B >> 7) * 8 + (B & 7);
    const int b = bh >> 4, h = bh & 15;

    const bf16_t* kbase = Kh + (size_t)bh * NSEQ * HD;
    const bf16_t* vbase = Vt + (size_t)bh * HD * NSEQ;

    // Hoist Q fragments straight from global (B-operand of swapped QK^T):
    // lane holds Q[q = qt*128 + wave*32 + l31][d = s*16 + hi*8 + j].
    bf16x8 qf[4];
    {
        const bf16_t* qrow =
            Qh + ((size_t)bh * NSEQ + qt * 128 + wave * 32 + l31) * HD + hi * 8;
        #pragma unroll
        for (int s = 0; s < 4; s++) qf[s] = *(const bf16x8*)(qrow + s * 16);
    }

    // Staging source pointers: thread covers chunks tid and tid+256 of the
    // 512-chunk (64 rows x 8) tile. LDS linear, global source pre-swizzled
    // (slot c holds global chunk c^(row&7)).
    const bf16_t *ks0, *ks1, *vs0, *vs1;
    {
        int r0 = tid >> 3, c0 = tid & 7;
        int s1 = tid + 256;
        int r1 = s1 >> 3, c1 = s1 & 7;
        ks0 = kbase + r0 * HD + (c0 ^ (r0 & 7)) * 8;
        ks1 = kbase + r1 * HD + (c1 ^ (r1 & 7)) * 8;
        vs0 = vbase + (size_t)r0 * NSEQ + (c0 ^ (r0 & 7)) * 8;
        vs1 = vbase + (size_t)r1 * NSEQ + (c1 ^ (r1 & 7)) * 8;
    }

    // Prologue: stage tile 0 into buffer 0.
    async_copy16(ks0, &Ks[0][tid * 8]);
    async_copy16(ks1, &Ks[0][(tid + 256) * 8]);
    async_copy16(vs0, &Vs[0][tid * 8]);
    async_copy16(vs1, &Vs[0][(tid + 256) * 8]);

    f32x16 oacc[2] = {};       // [d-tile]: O[q 32][d 32], row=q col=d
    float lp[4] = {};          // softmax denominator partials

    for (int t = 0; t < 32; t++) {
        const int cur = t & 1;
        __syncthreads();   // drains vmcnt -> tile t ready; prev reads of buf cur^1 done

        if (t < 31) {      // issue next tile into the other buffer (in flight across compute)
            ks0 += 64 * HD; ks1 += 64 * HD;
            vs0 += 64;      vs1 += 64;
            async_copy16(ks0, &Ks[cur ^ 1][tid * 8]);
            async_copy16(ks1, &Ks[cur ^ 1][(tid + 256) * 8]);
            async_copy16(vs0, &Vs[cur ^ 1][tid * 8]);
            async_copy16(vs1, &Vs[cur ^ 1][(tid + 256) * 8]);
        }

        // S^T = K Q^T: rows = kv (2 tiles of 32), cols = this wave's 32 q.
        // Slice s=0 peeled with a loop-invariant zero acc (no per-iter
        // v_mov zero-init of 32 regs).
        const f32x16 zero = {};
        f32x16 sacc0, sacc1;
        {
            int g = hi;
            int row0 = l31, row1 = 32 + l31;
            bf16x8 ak0 = *(const bf16x8*)&Ks[cur][row0 * 64 + ((g ^ (row0 & 7)) * 8)];
            bf16x8 ak1 = *(const bf16x8*)&Ks[cur][row1 * 64 + ((g ^ (row1 & 7)) * 8)];
            __builtin_amdgcn_s_setprio(1);
            sacc0 = __builtin_amdgcn_mfma_f32_32x32x16_bf16(ak0, qf[0], zero, 0, 0, 0);
            sacc1 = __builtin_amdgcn_mfma_f32_32x32x16_bf16(ak1, qf[0], zero, 0, 0, 0);
            __builtin_amdgcn_s_setprio(0);
        }
        #pragma unroll
        for (int s = 1; s < 4; s++) {
            int g = s * 2 + hi;           // d-chunk index
            int row0 = l31;               // kv 0..31
            int row1 = 32 + l31;          // kv 32..63
            bf16x8 ak0 = *(const bf16x8*)&Ks[cur][row0 * 64 + ((g ^ (row0 & 7)) * 8)];
            bf16x8 ak1 = *(const bf16x8*)&Ks[cur][row1 * 64 + ((g ^ (row1 & 7)) * 8)];
            __builtin_amdgcn_s_setprio(1);
            sacc0 = __builtin_amdgcn_mfma_f32_32x32x16_bf16(ak0, qf[s], sacc0, 0, 0, 0);
            sacc1 = __builtin_amdgcn_mfma_f32_32x32x16_bf16(ak1, qf[s], sacc1, 0, 0, 0);
            __builtin_amdgcn_s_setprio(0);
        }

        // In-register softmax + pack into 4 PV A-frags (kv 0..15,16..31,32..47,48..63)
        PW pa[4];
        softmax_pack(sacc0, lp, pa[0], pa[1]);
        softmax_pack(sacc1, lp, pa[2], pa[3]);

        // O += P V
        #pragma unroll
        for (int dt = 0; dt < 2; dt++) {
            #pragma unroll
            for (int ks = 0; ks < 4; ks++) {
                int row = dt * 32 + l31;          // d row in Vs
                int g = ks * 2 + hi;              // kv-chunk index
                bf16x8 bv = *(const bf16x8*)&Vs[cur][row * 64 + ((g ^ (row & 7)) * 8)];
                __builtin_amdgcn_s_setprio(1);
                oacc[dt] = __builtin_amdgcn_mfma_f32_32x32x16_bf16(
                    pa[ks].v, bv, oacc[dt], 0, 0, 0);
                __builtin_amdgcn_s_setprio(0);
            }
        }
    }

    // l[q] lives at lane q (both halves after xor-32 add); redistribute per reg.
    float lsum = (lp[0] + lp[1]) + (lp[2] + lp[3]);
    lsum += __shfl_xor(lsum, 32, 64);
    float linv = 1.f / lsum;
    float rinv[16];
    #pragma unroll
    for (int r = 0; r < 16; r++) {
        int q = (r & 3) + 8 * (r >> 2) + 4 * hi;
        rinv[r] = __shfl(linv, q, 64);
    }

    const int n0 = qt * 128 + wave * 32;
    #pragma unroll
    for (int dt = 0; dt < 2; dt++) {
        int c = h * 64 + dt * 32 + l31;
        #pragma unroll
        for (int r = 0; r < 16; r++) {
            int q = (r & 3) + 8 * (r >> 2) + 4 * hi;
            out[((size_t)b * NSEQ + n0 + q) * EDIM + c] = (bf16_t)(oacc[dt][r] * rinv[r]);
        }
    }
}

// ---------------------------------------------------------------------------
extern "C" void kernel_launch(void* const* d_in, const int* in_sizes, int n_in,
                              void* d_out, int out_size, void* d_ws, size_t ws_size,
                              hipStream_t stream) {
    const float* q  = (const float*)d_in[0];
    const float* k  = (const float*)d_in[1];
    const float* v  = (const float*)d_in[2];
    const float* wq = (const float*)d_in[3];
    const float* bq = (const float*)d_in[4];
    const float* wk = (const float*)d_in[5];
    const float* bk = (const float*)d_in[6];
    const float* wv = (const float*)d_in[7];
    const float* bv = (const float*)d_in[8];
    const float* wo = (const float*)d_in[9];
    const float* bo = (const float*)d_in[10];
    float* out = (float*)d_out;

    char* ws = (char*)d_ws;
    bf16_t* wqt = (bf16_t*)(ws + ((size_t)0  << 20)); // 2 MB each, bf16 NxK
    bf16_t* wkt = (bf16_t*)(ws + ((size_t)2  << 20));
    bf16_t* wvt = (bf16_t*)(ws + ((size_t)4  << 20));
    bf16_t* wot = (bf16_t*)(ws + ((size_t)6  << 20));

    const bool big = ws_size >= ((size_t)90 << 20);
    size_t off = big ? ((size_t)24 << 20) : ((size_t)8 << 20);
    bf16_t* X   = (bf16_t*)(ws + ((size_t)8 << 20));  // 16 MB bf16 A scratch (big only)
    bf16_t* Qh  = (bf16_t*)(ws + off);                              // 16 MB [b][h][n][d]
    bf16_t* Kh  = (bf16_t*)(ws + off + ((size_t)16 << 20));         // 16 MB [b][h][n][d]
    bf16_t* Vt  = (bf16_t*)(ws + off + ((size_t)32 << 20));         // 16 MB [b][h][d][n]
    bf16_t* ao  = (bf16_t*)(ws + off + ((size_t)48 << 20));         // 16 MB [b][n][INT]

    dim3 tb(256);

    transpose_all<<<dim3(16, 16, 4), tb, 0, stream>>>(wq, wk, wv, wo, wqt, wkt, wvt, wot);

    dim3 gg(8, 64);  // x = N-tiles (8), y = M-tiles (64): A-panel sharing
    if (big) {
        // Pre-convert A once -> pure async staging in the GEMMs (serialized reuse of X).
        cvt_f32_bf16<<<4096, tb, 0, stream>>>(q, X);
        gemm_nt<1, 0, bf16_t><<<gg, tb, 0, stream>>>(X, wqt, bq, Qh, 8192, 1024, 1024, QSCALE);
        cvt_f32_bf16<<<4096, tb, 0, stream>>>(k, X);
        gemm_nt<1, 0, bf16_t><<<gg, tb, 0, stream>>>(X, wkt, bk, Kh, 8192, 1024, 1024, 1.0f);
        cvt_f32_bf16<<<4096, tb, 0, stream>>>(v, X);
        gemm_nt<1, 1, bf16_t><<<gg, tb, 0, stream>>>(X, wvt, bv, Vt, 8192, 1024, 1024, 1.0f);
    } else {
        gemm_nt<0, 0, bf16_t><<<gg, tb, 0, stream>>>(q, wqt, bq, Qh, 8192, 1024, 1024, QSCALE);
        gemm_nt<0, 0, bf16_t><<<gg, tb, 0, stream>>>(k, wkt, bk, Kh, 8192, 1024, 1024, 1.0f);
        gemm_nt<0, 1, bf16_t><<<gg, tb, 0, stream>>>(v, wvt, bv, Vt, 8192, 1024, 1024, 1.0f);
    }

    attn_kernel<<<1024, tb, 0, stream>>>(Qh, Kh, Vt, ao);

    gemm_nt<1, 2, float><<<gg, tb, 0, stream>>>(ao, wot, bo, out, 8192, 1024, 1024, 1.0f);
}

// Round 3
// 346.315 us; speedup vs baseline: 1.2219x; 1.0718x over previous
//
#include <hip/hip_runtime.h>
#include <hip/hip_bf16.h>
#include <cstdint>
#include <cstddef>

// B=4, NQ=NK=2048, E=1024, H=16, HD=64, INT=1024.
// Interface (verified r4/r5): inputs f32, output f32, bf16 internals (thr 2%).
typedef __bf16 bf16_t;
typedef __bf16 bf16x8 __attribute__((ext_vector_type(8)));
typedef float f32x4 __attribute__((ext_vector_type(4)));
typedef float f32x16 __attribute__((ext_vector_type(16)));
typedef uint32_t u32;

#define EDIM 1024
#define HH 16
#define HD 64
#define NSEQ 2048
// fold 1/sqrt(64) * log2(e) into Q so softmax uses native exp2
#define QSCALE 0.18033688011f

__device__ __forceinline__ void async_copy16(const bf16_t* gsrc, bf16_t* lds_dst) {
    __builtin_amdgcn_global_load_lds(
        (const __attribute__((address_space(1))) uint32_t*)gsrc,
        (__attribute__((address_space(3))) uint32_t*)lds_dst,
        16, 0, 0);
}

// ---------------------------------------------------------------------------
// f32 -> bf16 bulk convert (8 elems/thread, exact cover for 8M elems).
// ---------------------------------------------------------------------------
__global__ void cvt_f32_bf16(const float* __restrict__ in, bf16_t* __restrict__ out) {
    size_t i = ((size_t)blockIdx.x * 256 + threadIdx.x) * 8;
    float4 x = *(const float4*)(in + i);
    float4 y = *(const float4*)(in + i + 4);
    bf16x8 v = {(bf16_t)x.x, (bf16_t)x.y, (bf16_t)x.z, (bf16_t)x.w,
                (bf16_t)y.x, (bf16_t)y.y, (bf16_t)y.z, (bf16_t)y.w};
    *(bf16x8*)(out + i) = v;
}

// ---------------------------------------------------------------------------
// Weight transpose + bf16 convert: W (1024x1024, KxN, f32) -> WT (NxK, bf16).
// ---------------------------------------------------------------------------
__global__ void transpose_all(const float* __restrict__ w0, const float* __restrict__ w1,
                              const float* __restrict__ w2, const float* __restrict__ w3,
                              bf16_t* __restrict__ o0, bf16_t* __restrict__ o1,
                              bf16_t* __restrict__ o2, bf16_t* __restrict__ o3) {
    __shared__ bf16_t t[64][65];
    const float* in;
    bf16_t* out;
    switch (blockIdx.z) {
        case 0: in = w0; out = o0; break;
        case 1: in = w1; out = o1; break;
        case 2: in = w2; out = o2; break;
        default: in = w3; out = o3; break;
    }
    const int tid = threadIdx.x;
    const int kt = blockIdx.x, nt = blockIdx.y;
    #pragma unroll
    for (int i = 0; i < 16; i++) {
        int idx = i * 256 + tid;
        int r = idx >> 6, c = idx & 63;
        t[r][c] = (bf16_t)in[(size_t)(kt * 64 + r) * 1024 + nt * 64 + c];
    }
    __syncthreads();
    #pragma unroll
    for (int i = 0; i < 16; i++) {
        int idx = i * 256 + tid;
        int r = idx >> 6, c = idx & 63;
        out[(size_t)(nt * 64 + r) * 1024 + kt * 64 + c] = t[c][r];
    }
}

// ---------------------------------------------------------------------------
// NT GEMM: C(MxN) = A(MxK) * Bt(NxK)^T + bias. 128x128 tile, BK=64,
// double-buffered LDS (one barrier per K-step, loads for t+1 in flight
// across compute of t -- same 2-phase idiom as the attn kernel).
// Rows are 64 bf16 = 128 B; XOR swizzle slot c <- global chunk c^(row&7)
// (the attn-verified pattern). 32 MFMA per barrier.
// XCD remap: work_m = (by>>3)*8+bx, work_n = by&7 -> all 8 N-blocks that
// share an A-panel have the same lin%8 (= bx) -> same XCD -> A-panel and
// B stay L2-resident (B 2MB, 8x reuse per XCD).
// AB=0: A f32 (inline convert). AB=1: A bf16 (async global_load_lds).
// MODE 0: head-major [b][h][n][d] bf16 * oscale   (Q, K projections)
// MODE 1: transposed [b][h][d][n] bf16            (V projection)
// MODE 2: row-major MxN, OUT dtype                (output projection)
// ---------------------------------------------------------------------------
template <int AB, int MODE, typename OUT>
__global__ __launch_bounds__(256, 2)
void gemm_nt(const void* __restrict__ Araw, const bf16_t* __restrict__ Bt,
             const float* __restrict__ bias, OUT* __restrict__ C,
             int M, int N, int K, float oscale) {
    constexpr int BM = 128, BN = 128, BK = 64;
    __shared__ bf16_t Asm[2][BM * BK];   // 2 x 16 KB
    __shared__ bf16_t Bsm[2][BN * BK];   // 2 x 16 KB
    const int tid = threadIdx.x;
    const int wave = tid >> 6, lane = tid & 63;
    const int quad = lane >> 4, l15 = lane & 15;
    // XCD-aware remap (bijective): cluster the 8 N-tiles of one M-row on one XCD.
    const int bx = blockIdx.x, by = blockIdx.y;
    const int n0 = (by & 7) * BN;
    const int m0 = ((by >> 3) * 8 + bx) * BM;
    const int wm = (wave & 1) * 64, wn = (wave >> 1) * 64;

    // Per-thread staging coords: 4 chunks per operand tile (128 rows x 8 chunks).
    const int srow = tid >> 1;                 // rows 0..127 (2 threads/row)
    const int NT = K / BK;                     // 16 K-steps

    f32x4 acc[4][4] = {};

    // --- staging helper (A bf16 path + B), swizzled source, linear LDS dest ---
    const bf16_t* Ab = (const bf16_t*)Araw;
    const float* Af = (const float*)Araw;

    auto stage = [&](int t, int buf) {
        const int k0 = t * BK;
        #pragma unroll
        for (int i = 0; i < 4; i++) {
            int s = i * 256 + tid;
            int row = s >> 3, c = s & 7;
            int kc = c ^ (row & 7);
            if (AB) {
                async_copy16(Ab + (size_t)(m0 + row) * K + k0 + kc * 8, &Asm[buf][s * 8]);
            } else {
                const float* sp = Af + (size_t)(m0 + row) * K + k0 + kc * 8;
                float4 x = *(const float4*)sp;
                float4 y = *(const float4*)(sp + 4);
                bf16x8 vv = {(bf16_t)x.x, (bf16_t)x.y, (bf16_t)x.z, (bf16_t)x.w,
                             (bf16_t)y.x, (bf16_t)y.y, (bf16_t)y.z, (bf16_t)y.w};
                *(bf16x8*)&Asm[buf][s * 8] = vv;
            }
        }
        #pragma unroll
        for (int i = 0; i < 4; i++) {
            int s = i * 256 + tid;
            int row = s >> 3, c = s & 7;
            int kc = c ^ (row & 7);
            async_copy16(Bt + (size_t)(n0 + row) * K + k0 + kc * 8, &Bsm[buf][s * 8]);
        }
    };

    // Prologue: stage tile 0 into buffer 0.
    stage(0, 0);

    for (int t = 0; t < NT; t++) {
        const int buf = t & 1;
        __syncthreads();   // drains vmcnt -> tile t ready; prev reads of buf^1 done

        if (t + 1 < NT) stage(t + 1, buf ^ 1);   // in flight across this compute

        bf16x8 af[2][4], bfr[2][4];
        #pragma unroll
        for (int ks = 0; ks < 2; ks++) {
            #pragma unroll
            for (int mi = 0; mi < 4; mi++) {
                int row = wm + mi * 16 + l15;
                int g = ks * 4 + quad;
                af[ks][mi] = *(const bf16x8*)&Asm[buf][row * BK + ((g ^ (row & 7)) * 8)];
            }
            #pragma unroll
            for (int ni = 0; ni < 4; ni++) {
                int row = wn + ni * 16 + l15;
                int g = ks * 4 + quad;
                bfr[ks][ni] = *(const bf16x8*)&Bsm[buf][row * BK + ((g ^ (row & 7)) * 8)];
            }
        }
        #pragma unroll
        for (int ks = 0; ks < 2; ks++)
            #pragma unroll
            for (int mi = 0; mi < 4; mi++)
                #pragma unroll
                for (int ni = 0; ni < 4; ni++)
                    acc[mi][ni] = __builtin_amdgcn_mfma_f32_16x16x32_bf16(
                        af[ks][mi], bfr[ks][ni], acc[mi][ni], 0, 0, 0);
    }

    // Epilogue. C/D layout: row = quad*4 + r, col = l15 (verified m89/m91).
    #pragma unroll
    for (int mi = 0; mi < 4; mi++) {
        #pragma unroll
        for (int ni = 0; ni < 4; ni++) {
            #pragma unroll
            for (int r = 0; r < 4; r++) {
                int m = m0 + wm + mi * 16 + quad * 4 + r;
                int nch = n0 + wn + ni * 16 + l15;
                float v = (acc[mi][ni][r] + bias[nch]) * oscale;
                if (MODE == 2) {
                    C[(size_t)m * N + nch] = (OUT)v;
                } else {
                    int b = m >> 11, n = m & 2047;
                    int h = nch >> 6, d = nch & 63;
                    if (MODE == 0)
                        C[(((size_t)(b * HH + h)) * NSEQ + n) * HD + d] = (OUT)v;
                    else
                        C[(((size_t)(b * HH + h)) * HD + d) * NSEQ + n] = (OUT)v;
                }
            }
        }
    }
}

// ---------------------------------------------------------------------------
// Flash attention, swapped-QK^T in-register softmax (m214 structure).
// Grid 1024 blocks x 256 thr (4 waves). Wave owns 32 q-rows; kv-tile 64;
// 32 iters. XCD clustering: xcd=B&7, qt=(B>>3)&15, bh=(B>>7)*8+xcd (all 16
// q-blocks of a bh on one XCD -> 512 KB K/V slab L2-resident, 8 bh/XCD).
//
// QK^T computed SWAPPED: S^T = mfma_32x32x16(A=K, B=Q) so each lane holds a
// full P column (q = lane&31) in registers: p[r] = P[q][(r&3)+8*(r>>2)+4*hi].
// Softmax fully in-register (fixed-max: Q pre-scaled, p=exp2(s)); P->bf16
// pack (v_cvt_pk) + v_permlane32_swap assembles PV's A-fragments directly --
// NO P round-trip through LDS, no ds_bpermute.
// K/V double-buffered in LDS, one barrier per iter (T3 minimum 2-phase).
// launch_bounds(256,2): 256 unified regs/wave so sacc/oacc/pa all live in
// VGPRs -- no v_accvgpr_read/write traffic in the softmax.
// Qh, Kh: [bh][n][d] bf16. Vt: [bh][d][n] bf16. Out ao: [b][n][INT] bf16.
// ---------------------------------------------------------------------------
union PW { u32 w[4]; bf16x8 v; };

__device__ __forceinline__ u32 pack_bf16(float lo, float hi) {
    union { bf16_t h[2]; u32 u; } x;
    x.h[0] = (bf16_t)lo;
    x.h[1] = (bf16_t)hi;
    return x.u;   // compiler emits v_cvt_pk_bf16_f32
}

// v_permlane32_swap_b32: new_a = {a.lanes0-31, b.lanes0-31},
//                        new_b = {a.lanes32-63, b.lanes32-63}.
__device__ __forceinline__ void half_swap(u32& a, u32& b) {
    auto r = __builtin_amdgcn_permlane32_swap(a, b, false, false);
    a = r[0];
    b = r[1];
}

// p[r] of one 32x32 S^T tile -> exp2 -> two PV A-frags (kv 0..15, 16..31).
__device__ __forceinline__ void softmax_pack(const f32x16 sa, float* lp,
                                             PW& f0, PW& f1) {
    float p[16];
    #pragma unroll
    for (int r = 0; r < 16; r++) {
        p[r] = __builtin_amdgcn_exp2f(sa[r]);   // single v_exp_f32
        lp[r & 3] += p[r];   // 4 partial chains (breaks serial fadd dep)
    }
    u32 x0 = pack_bf16(p[0],  p[1]),  x1 = pack_bf16(p[2],  p[3]);
    u32 x2 = pack_bf16(p[4],  p[5]),  x3 = pack_bf16(p[6],  p[7]);
    u32 x4 = pack_bf16(p[8],  p[9]),  x5 = pack_bf16(p[10], p[11]);
    u32 x6 = pack_bf16(p[12], p[13]), x7 = pack_bf16(p[14], p[15]);
    half_swap(x0, x2); half_swap(x1, x3);
    half_swap(x4, x6); half_swap(x5, x7);
    f0.w[0] = x0; f0.w[1] = x1; f0.w[2] = x2; f0.w[3] = x3;
    f1.w[0] = x4; f1.w[1] = x5; f1.w[2] = x6; f1.w[3] = x7;
}

__global__ __launch_bounds__(256, 2)
void attn_kernel(const bf16_t* __restrict__ Qh, const bf16_t* __restrict__ Kh,
                 const bf16_t* __restrict__ Vt, bf16_t* __restrict__ out) {
    __shared__ bf16_t Ks[2][64 * 64];   // 16 KB: kv-tile, [kv][d], chunk-swizzled
    __shared__ bf16_t Vs[2][64 * 64];   // 16 KB: kv-tile, [d][kv], chunk-swizzled
    const int tid = threadIdx.x, wave = tid >> 6, lane = tid & 63;
    const int l31 = lane & 31, hi = lane >> 5;
    const int B = blockIdx.x;
    const int qt = (B >> 3) & 15;
    const int bh = (B >> 7) * 8 + (B & 7);
    const int b = bh >> 4, h = bh & 15;

    const bf16_t* kbase = Kh + (size_t)bh * NSEQ * HD;
    const bf16_t* vbase = Vt + (size_t)bh * HD * NSEQ;

    // Hoist Q fragments straight from global (B-operand of swapped QK^T):
    // lane holds Q[q = qt*128 + wave*32 + l31][d = s*16 + hi*8 + j].
    bf16x8 qf[4];
    {
        const bf16_t* qrow =
            Qh + ((size_t)bh * NSEQ + qt * 128 + wave * 32 + l31) * HD + hi * 8;
        #pragma unroll
        for (int s = 0; s < 4; s++) qf[s] = *(const bf16x8*)(qrow + s * 16);
    }

    // Staging source pointers: thread covers chunks tid and tid+256 of the
    // 512-chunk (64 rows x 8) tile. LDS linear, global source pre-swizzled
    // (slot c holds global chunk c^(row&7)).
    const bf16_t *ks0, *ks1, *vs0, *vs1;
    {
        int r0 = tid >> 3, c0 = tid & 7;
        int s1 = tid + 256;
        int r1 = s1 >> 3, c1 = s1 & 7;
        ks0 = kbase + r0 * HD + (c0 ^ (r0 & 7)) * 8;
        ks1 = kbase + r1 * HD + (c1 ^ (r1 & 7)) * 8;
        vs0 = vbase + (size_t)r0 * NSEQ + (c0 ^ (r0 & 7)) * 8;
        vs1 = vbase + (size_t)r1 * NSEQ + (c1 ^ (r1 & 7)) * 8;
    }

    // Prologue: stage tile 0 into buffer 0.
    async_copy16(ks0, &Ks[0][tid * 8]);
    async_copy16(ks1, &Ks[0][(tid + 256) * 8]);
    async_copy16(vs0, &Vs[0][tid * 8]);
    async_copy16(vs1, &Vs[0][(tid + 256) * 8]);

    f32x16 oacc[2] = {};       // [d-tile]: O[q 32][d 32], row=q col=d
    float lp[4] = {};          // softmax denominator partials

    for (int t = 0; t < 32; t++) {
        const int cur = t & 1;
        __syncthreads();   // drains vmcnt -> tile t ready; prev reads of buf cur^1 done

        if (t < 31) {      // issue next tile into the other buffer (in flight across compute)
            ks0 += 64 * HD; ks1 += 64 * HD;
            vs0 += 64;      vs1 += 64;
            async_copy16(ks0, &Ks[cur ^ 1][tid * 8]);
            async_copy16(ks1, &Ks[cur ^ 1][(tid + 256) * 8]);
            async_copy16(vs0, &Vs[cur ^ 1][tid * 8]);
            async_copy16(vs1, &Vs[cur ^ 1][(tid + 256) * 8]);
        }

        // S^T = K Q^T: rows = kv (2 tiles of 32), cols = this wave's 32 q.
        // Slice s=0 peeled with a loop-invariant zero acc.
        const f32x16 zero = {};
        f32x16 sacc0, sacc1;
        {
            int g = hi;
            int row0 = l31, row1 = 32 + l31;
            bf16x8 ak0 = *(const bf16x8*)&Ks[cur][row0 * 64 + ((g ^ (row0 & 7)) * 8)];
            bf16x8 ak1 = *(const bf16x8*)&Ks[cur][row1 * 64 + ((g ^ (row1 & 7)) * 8)];
            __builtin_amdgcn_s_setprio(1);
            sacc0 = __builtin_amdgcn_mfma_f32_32x32x16_bf16(ak0, qf[0], zero, 0, 0, 0);
            sacc1 = __builtin_amdgcn_mfma_f32_32x32x16_bf16(ak1, qf[0], zero, 0, 0, 0);
            __builtin_amdgcn_s_setprio(0);
        }
        #pragma unroll
        for (int s = 1; s < 4; s++) {
            int g = s * 2 + hi;           // d-chunk index
            int row0 = l31;               // kv 0..31
            int row1 = 32 + l31;          // kv 32..63
            bf16x8 ak0 = *(const bf16x8*)&Ks[cur][row0 * 64 + ((g ^ (row0 & 7)) * 8)];
            bf16x8 ak1 = *(const bf16x8*)&Ks[cur][row1 * 64 + ((g ^ (row1 & 7)) * 8)];
            __builtin_amdgcn_s_setprio(1);
            sacc0 = __builtin_amdgcn_mfma_f32_32x32x16_bf16(ak0, qf[s], sacc0, 0, 0, 0);
            sacc1 = __builtin_amdgcn_mfma_f32_32x32x16_bf16(ak1, qf[s], sacc1, 0, 0, 0);
            __builtin_amdgcn_s_setprio(0);
        }

        // In-register softmax + pack into 4 PV A-frags (kv 0..15,16..31,32..47,48..63)
        PW pa[4];
        softmax_pack(sacc0, lp, pa[0], pa[1]);
        softmax_pack(sacc1, lp, pa[2], pa[3]);

        // O += P V
        #pragma unroll
        for (int dt = 0; dt < 2; dt++) {
            #pragma unroll
            for (int ks = 0; ks < 4; ks++) {
                int row = dt * 32 + l31;          // d row in Vs
                int g = ks * 2 + hi;              // kv-chunk index
                bf16x8 bv = *(const bf16x8*)&Vs[cur][row * 64 + ((g ^ (row & 7)) * 8)];
                __builtin_amdgcn_s_setprio(1);
                oacc[dt] = __builtin_amdgcn_mfma_f32_32x32x16_bf16(
                    pa[ks].v, bv, oacc[dt], 0, 0, 0);
                __builtin_amdgcn_s_setprio(0);
            }
        }
    }

    // l[q] lives at lane q (both halves after xor-32 add); redistribute per reg.
    float lsum = (lp[0] + lp[1]) + (lp[2] + lp[3]);
    lsum += __shfl_xor(lsum, 32, 64);
    float linv = 1.f / lsum;
    float rinv[16];
    #pragma unroll
    for (int r = 0; r < 16; r++) {
        int q = (r & 3) + 8 * (r >> 2) + 4 * hi;
        rinv[r] = __shfl(linv, q, 64);
    }

    const int n0 = qt * 128 + wave * 32;
    #pragma unroll
    for (int dt = 0; dt < 2; dt++) {
        int c = h * 64 + dt * 32 + l31;
        #pragma unroll
        for (int r = 0; r < 16; r++) {
            int q = (r & 3) + 8 * (r >> 2) + 4 * hi;
            out[((size_t)b * NSEQ + n0 + q) * EDIM + c] = (bf16_t)(oacc[dt][r] * rinv[r]);
        }
    }
}

// ---------------------------------------------------------------------------
extern "C" void kernel_launch(void* const* d_in, const int* in_sizes, int n_in,
                              void* d_out, int out_size, void* d_ws, size_t ws_size,
                              hipStream_t stream) {
    const float* q  = (const float*)d_in[0];
    const float* k  = (const float*)d_in[1];
    const float* v  = (const float*)d_in[2];
    const float* wq = (const float*)d_in[3];
    const float* bq = (const float*)d_in[4];
    const float* wk = (const float*)d_in[5];
    const float* bk = (const float*)d_in[6];
    const float* wv = (const float*)d_in[7];
    const float* bv = (const float*)d_in[8];
    const float* wo = (const float*)d_in[9];
    const float* bo = (const float*)d_in[10];
    float* out = (float*)d_out;

    char* ws = (char*)d_ws;
    bf16_t* wqt = (bf16_t*)(ws + ((size_t)0  << 20)); // 2 MB each, bf16 NxK
    bf16_t* wkt = (bf16_t*)(ws + ((size_t)2  << 20));
    bf16_t* wvt = (bf16_t*)(ws + ((size_t)4  << 20));
    bf16_t* wot = (bf16_t*)(ws + ((size_t)6  << 20));

    const bool big = ws_size >= ((size_t)90 << 20);
    size_t off = big ? ((size_t)24 << 20) : ((size_t)8 << 20);
    bf16_t* X   = (bf16_t*)(ws + ((size_t)8 << 20));  // 16 MB bf16 A scratch (big only)
    bf16_t* Qh  = (bf16_t*)(ws + off);                              // 16 MB [b][h][n][d]
    bf16_t* Kh  = (bf16_t*)(ws + off + ((size_t)16 << 20));         // 16 MB [b][h][n][d]
    bf16_t* Vt  = (bf16_t*)(ws + off + ((size_t)32 << 20));         // 16 MB [b][h][d][n]
    bf16_t* ao  = (bf16_t*)(ws + off + ((size_t)48 << 20));         // 16 MB [b][n][INT]

    dim3 tb(256);

    transpose_all<<<dim3(16, 16, 4), tb, 0, stream>>>(wq, wk, wv, wo, wqt, wkt, wvt, wot);

    dim3 gg(8, 64);  // remapped in-kernel: 8 N-tiles x 64 M-tiles, XCD-clustered
    if (big) {
        // Pre-convert A once -> pure async staging in the GEMMs (serialized reuse of X).
        cvt_f32_bf16<<<4096, tb, 0, stream>>>(q, X);
        gemm_nt<1, 0, bf16_t><<<gg, tb, 0, stream>>>(X, wqt, bq, Qh, 8192, 1024, 1024, QSCALE);
        cvt_f32_bf16<<<4096, tb, 0, stream>>>(k, X);
        gemm_nt<1, 0, bf16_t><<<gg, tb, 0, stream>>>(X, wkt, bk, Kh, 8192, 1024, 1024, 1.0f);
        cvt_f32_bf16<<<4096, tb, 0, stream>>>(v, X);
        gemm_nt<1, 1, bf16_t><<<gg, tb, 0, stream>>>(X, wvt, bv, Vt, 8192, 1024, 1024, 1.0f);
    } else {
        gemm_nt<0, 0, bf16_t><<<gg, tb, 0, stream>>>(q, wqt, bq, Qh, 8192, 1024, 1024, QSCALE);
        gemm_nt<0, 0, bf16_t><<<gg, tb, 0, stream>>>(k, wkt, bk, Kh, 8192, 1024, 1024, 1.0f);
        gemm_nt<0, 1, bf16_t><<<gg, tb, 0, stream>>>(v, wvt, bv, Vt, 8192, 1024, 1024, 1.0f);
    }

    attn_kernel<<<1024, tb, 0, stream>>>(Qh, Kh, Vt, ao);

    gemm_nt<1, 2, float><<<gg, tb, 0, stream>>>(ao, wot, bo, out, 8192, 1024, 1024, 1.0f);
}